// Round 5
// baseline (2102.881 us; speedup 1.0000x reference)
//
#include <hip/hip_runtime.h>
#include <stdint.h>

// ---------------------------------------------------------------------------
// Net_29137058136132: ImgEncoder (2048->512) + 6x Rs_GCN non-local blocks.
// B=256, N=100, C=512, DIMG=2048, L=6. fp32 in/out; bf16 MFMA, fp32 accum.
// Residual master x = fp32 in d_out. Attention middle (g-proj, R, y) fused
// into k_gattn: R and transposed-g live in LDS (63.4KB), y overwrites th.
// Base ws = 64 MiB (always fits); optional y-split / xb / imgb on ws_size.
// ---------------------------------------------------------------------------

typedef __bf16 bf16;
typedef float  f32x4  __attribute__((ext_vector_type(4)));
typedef bf16   bf16x4 __attribute__((ext_vector_type(4)));
typedef bf16   bf16x8 __attribute__((ext_vector_type(8)));

#define MTOT   25600   // 256*100 rows
#define CDIM   512
#define NTOK   100
#define RPAD   128
#define BN_EPS 1e-5f
#define NW_T   (2048 * 512)
#define NW_L   (6 * 512 * 512)

__device__ __forceinline__ void gload16(const bf16* gsrc, bf16* lds_dst)
{
    __builtin_amdgcn_global_load_lds(
        (const __attribute__((address_space(1))) void*)gsrc,
        (__attribute__((address_space(3))) void*)lds_dst,
        16, 0, 0);
}

// ---------------- fp32 -> bf16 elementwise convert (n % 4 == 0) ------------
__global__ __launch_bounds__(256) void k_cvt(const float* __restrict__ s,
                                             bf16* __restrict__ d, int n)
{
    const int i = (blockIdx.x * 256 + threadIdx.x) * 4;
    if (i < n) {
        const f32x4 v = *(const f32x4*)(s + i);
        bf16x4 o;
#pragma unroll
        for (int e = 0; e < 4; ++e) o[e] = (bf16)v[e];
        *(bf16x4*)(d + i) = o;
    }
}

__global__ __launch_bounds__(256) void k_cvtw(const float* tw, const float* gw,
                                              const float* t2, const float* pw,
                                              const float* wwp,
                                              bf16* twd, bf16* gwd, bf16* t2d,
                                              bf16* pwd, bf16* wwd)
{
    const float* s; bf16* d; int n;
    switch (blockIdx.z) {
        case 0: s = tw;  d = twd; n = NW_T; break;
        case 1: s = gw;  d = gwd; n = NW_L; break;
        case 2: s = t2;  d = t2d; n = NW_L; break;
        case 3: s = pw;  d = pwd; n = NW_L; break;
        default: s = wwp; d = wwd; n = NW_L; break;
    }
    const int i = (blockIdx.x * 256 + threadIdx.x) * 4;
    if (i < n) {
        const f32x4 v = *(const f32x4*)(s + i);
        bf16x4 o;
#pragma unroll
        for (int e = 0; e < 4; ++e) o[e] = (bf16)v[e];
        *(bf16x4*)(d + i) = o;
    }
}

// ---------------------------------------------------------------------------
// 128x128-tile GEMM mainloop (m97 structure), BK=32, K%32==0.
// ---------------------------------------------------------------------------
template<bool ABF>
__device__ __forceinline__ void gemm_tile(const void* __restrict__ Av,
                                          const bf16* __restrict__ W,
                                          int K, int m0, int n0,
                                          bf16* As, bf16* Bs, f32x4 acc[4][4])
{
    const int tid  = threadIdx.x;
    const int lane = tid & 63, wave = tid >> 6;
    const int lrow = lane & 15, quad = lane >> 4;
    const int wm = (wave & 1) * 64, wn = (wave >> 1) * 64;
    const int r0 = tid >> 2;
    const int kp = (tid & 3) * 8;

    const bf16* Wb0 = W + (size_t)(n0 + r0) * K + kp;
    const bf16* Wb1 = Wb0 + (size_t)64 * K;
    bf16* As0 = As + tid * 8;
    bf16* Bs0 = Bs + tid * 8;

    const bf16*  Ab0 = ABF ? (const bf16*)Av + (size_t)(m0 + r0) * K + kp : (const bf16*)nullptr;
    const bf16*  Ab1 = ABF ? Ab0 + (size_t)64 * K : (const bf16*)nullptr;
    const float* Af0 = ABF ? (const float*)nullptr : (const float*)Av + (size_t)(m0 + r0) * K + kp;
    const float* Af1 = ABF ? (const float*)nullptr : Af0 + (size_t)64 * K;

    for (int kt = 0; kt < K; kt += 32) {
        bf16x8 av0, av1;
        if (!ABF) {
            const f32x4 a0 = *(const f32x4*)(Af0 + kt);
            const f32x4 a1 = *(const f32x4*)(Af0 + kt + 4);
            const f32x4 a2 = *(const f32x4*)(Af1 + kt);
            const f32x4 a3 = *(const f32x4*)(Af1 + kt + 4);
#pragma unroll
            for (int e = 0; e < 4; ++e) {
                av0[e] = (bf16)a0[e]; av0[e + 4] = (bf16)a1[e];
                av1[e] = (bf16)a2[e]; av1[e + 4] = (bf16)a3[e];
            }
        }
        __syncthreads();
        if (ABF) {
            gload16(Ab0 + kt, As0);
            gload16(Ab1 + kt, As0 + 2048);
        } else {
            *(bf16x8*)As0          = av0;
            *(bf16x8*)(As0 + 2048) = av1;
        }
        gload16(Wb0 + kt, Bs0);
        gload16(Wb1 + kt, Bs0 + 2048);
        __syncthreads();

        bf16x8 af[4], bv[4];
#pragma unroll
        for (int i = 0; i < 4; ++i)
            af[i] = *(const bf16x8*)(As + (wm + i * 16 + lrow) * 32 + quad * 8);
#pragma unroll
        for (int j = 0; j < 4; ++j)
            bv[j] = *(const bf16x8*)(Bs + (wn + j * 16 + lrow) * 32 + quad * 8);
#pragma unroll
        for (int i = 0; i < 4; ++i)
#pragma unroll
            for (int j = 0; j < 4; ++j)
                acc[i][j] = __builtin_amdgcn_mfma_f32_16x16x32_bf16(
                    af[i], bv[j], acc[i][j], 0, 0, 0);
    }
}

// ---------------- Encoder ---------------------------------------------------
template<bool ABF>
__global__ __launch_bounds__(256) void k_enc(const void* __restrict__ img,
                                             const bf16* __restrict__ Wt,
                                             const float* __restrict__ bias,
                                             float* __restrict__ xf,
                                             bf16* __restrict__ xb)
{
    __shared__ __align__(16) bf16 As[128 * 32];
    __shared__ __align__(16) bf16 Bs[128 * 32];
    const int m0 = blockIdx.y * 128, n0 = blockIdx.x * 128;
    f32x4 acc[4][4] = {};
    gemm_tile<ABF>(img, Wt, 2048, m0, n0, As, Bs, acc);

    const int tid = threadIdx.x, wave = tid >> 6, lane = tid & 63;
    const int lrow = lane & 15, quad = lane >> 4;
    const int wm = (wave & 1) * 64, wn = (wave >> 1) * 64;
#pragma unroll
    for (int j = 0; j < 4; ++j) {
        const int col = n0 + wn + j * 16 + lrow;
        const float b = bias[col];
#pragma unroll
        for (int i = 0; i < 4; ++i) {
            const int row0 = m0 + wm + i * 16 + quad * 4;
#pragma unroll
            for (int r = 0; r < 4; ++r) {
                const size_t idx = (size_t)(row0 + r) * CDIM + col;
                const float v = acc[i][j][r] + b;
                xf[idx] = v;
                if (xb) xb[idx] = (bf16)v;
            }
        }
    }
}

// ---------------- th/ph projections (z picks which) ------------------------
template<bool ABF>
__global__ __launch_bounds__(256) void k_proj2(const void* __restrict__ x,
                                               const bf16* __restrict__ W0, const float* __restrict__ b0,
                                               bf16* __restrict__ o0,
                                               const bf16* __restrict__ W1, const float* __restrict__ b1,
                                               bf16* __restrict__ o1)
{
    __shared__ __align__(16) bf16 As[128 * 32];
    __shared__ __align__(16) bf16 Bs[128 * 32];
    const bf16*  W    = blockIdx.z ? W1 : W0;
    const float* bias = blockIdx.z ? b1 : b0;
    bf16*        out  = blockIdx.z ? o1 : o0;

    const int m0 = blockIdx.y * 128, n0 = blockIdx.x * 128;
    f32x4 acc[4][4] = {};
    gemm_tile<ABF>(x, W, 512, m0, n0, As, Bs, acc);

    const int tid = threadIdx.x, wave = tid >> 6, lane = tid & 63;
    const int lrow = lane & 15, quad = lane >> 4;
    const int wm = (wave & 1) * 64, wn = (wave >> 1) * 64;
#pragma unroll
    for (int j = 0; j < 4; ++j) {
        const int col = n0 + wn + j * 16 + lrow;
        const float b = bias[col];
#pragma unroll
        for (int i = 0; i < 4; ++i) {
            const int row0 = m0 + wm + i * 16 + quad * 4;
#pragma unroll
            for (int r = 0; r < 4; ++r)
                out[(size_t)(row0 + r) * CDIM + col] = (bf16)(acc[i][j][r] + b);
        }
    }
}

// ---------------- W-proj + BN(eval) + residual -----------------------------
__global__ __launch_bounds__(256) void k_wproj(const bf16* __restrict__ Y,
                                               const bf16* __restrict__ Wt,
                                               const float* __restrict__ bias,
                                               const float* __restrict__ bng, const float* __restrict__ bnb,
                                               const float* __restrict__ bnm, const float* __restrict__ bnv,
                                               float* __restrict__ xf,
                                               bf16* __restrict__ xb)
{
    __shared__ __align__(16) bf16 As[128 * 32];
    __shared__ __align__(16) bf16 Bs[128 * 32];
    const int m0 = blockIdx.y * 128, n0 = blockIdx.x * 128;
    f32x4 acc[4][4] = {};
    gemm_tile<true>(Y, Wt, 512, m0, n0, As, Bs, acc);

    const int tid = threadIdx.x, wave = tid >> 6, lane = tid & 63;
    const int lrow = lane & 15, quad = lane >> 4;
    const int wm = (wave & 1) * 64, wn = (wave >> 1) * 64;
#pragma unroll
    for (int j = 0; j < 4; ++j) {
        const int col = n0 + wn + j * 16 + lrow;
        const float sc = bng[col] * rsqrtf(bnv[col] + BN_EPS);
        const float sh = (bias[col] - bnm[col]) * sc + bnb[col];
#pragma unroll
        for (int i = 0; i < 4; ++i) {
            const int row0 = m0 + wm + i * 16 + quad * 4;
#pragma unroll
            for (int r = 0; r < 4; ++r) {
                const size_t idx = (size_t)(row0 + r) * CDIM + col;
                const float v = xf[idx] + acc[i][j][r] * sc + sh;
                xf[idx] = v;
                if (xb) xb[idx] = (bf16)v;
            }
        }
    }
}

// ---------------------------------------------------------------------------
// Fused attention middle: per batch b,
//   phase1: R = th_b @ ph_b^T / 100  -> Rs (LDS, k-XOR-swizzled, zero-padded)
//   per 128-col chunk: phase0 g_chunk = x_b @ gw^T + gb -> gT (LDS, transposed,
//   stride 136); phase2 y_chunk = R @ g_chunk -> Y global.
// 512 threads (8 waves). grid (nsplit, 256); block does cpb=4/nsplit chunks.
// With nsplit=1, Y may alias TH (block owns its batch rows, syncs internally).
// ---------------------------------------------------------------------------
template<bool ABF>
__global__ __launch_bounds__(512) void k_gattn(const void* __restrict__ X,
                                               const bf16* __restrict__ GW,
                                               const float* __restrict__ GB,
                                               const bf16* __restrict__ TH,
                                               const bf16* __restrict__ PH,
                                               bf16* __restrict__ Y, int cpb)
{
    __shared__ __align__(16) bf16 Rs[112 * 128];   // 28.0 KiB
    __shared__ __align__(16) bf16 gT[128 * 136];   // 34.0 KiB
    const int b = blockIdx.y;
    const int tid = threadIdx.x, wave = tid >> 6, lane = tid & 63;
    const int lrow = lane & 15, quad = lane >> 4;

    const bf16* th = TH + (size_t)b * NTOK * CDIM;
    const bf16* ph = PH + (size_t)b * NTOK * CDIM;

    // zero Rs fully + gT pad rows (m' in [112,136) for all 128 cols)
    {
        uint32_t* r32 = (uint32_t*)Rs;
#pragma unroll
        for (int i = 0; i < 14; ++i) r32[tid + i * 512] = 0u;   // 112*128/2 = 7168
        uint32_t* g32 = (uint32_t*)gT;
#pragma unroll
        for (int i = 0; i < 3; ++i) {
            const int t  = tid + i * 512;    // 0..1535
            const int c  = t / 12, mi = t % 12;
            g32[c * 68 + 56 + mi] = 0u;      // bf16 pair (112+2*mi, +1)
        }
    }
    __syncthreads();

    // ---- phase 1: R -> Rs ----
    if (wave < 7) {
        f32x4 acc[7] = {};
        int arow = wave * 16 + lrow; if (arow > 99) arow = 99;
        for (int kt = 0; kt < CDIM; kt += 32) {
            const bf16x8 af = *(const bf16x8*)(th + (size_t)arow * CDIM + kt + quad * 8);
#pragma unroll
            for (int j = 0; j < 7; ++j) {
                int brow = j * 16 + lrow; if (brow > 99) brow = 99;
                const bf16x8 bv = *(const bf16x8*)(ph + (size_t)brow * CDIM + kt + quad * 8);
                acc[j] = __builtin_amdgcn_mfma_f32_16x16x32_bf16(af, bv, acc[j], 0, 0, 0);
            }
        }
#pragma unroll
        for (int j = 0; j < 7; ++j) {
            const int col = j * 16 + lrow;
#pragma unroll
            for (int r = 0; r < 4; ++r) {
                const int row = wave * 16 + quad * 4 + r;
                if (row < NTOK && col < NTOK)
                    Rs[row * 128 + (col ^ ((row & 7) * 8))] = (bf16)(acc[j][r] * 0.01f);
            }
        }
    }
    __syncthreads();

    // ---- per column chunk: phase0 (g -> gT) then phase2 (y = R @ g) ----
    const int c_loc = wave * 16 + lrow;              // 0..127
    int xr[7];
#pragma unroll
    for (int mt = 0; mt < 7; ++mt) { int m = mt * 16 + lrow; xr[mt] = m > 99 ? 99 : m; }

    for (int ci = 0; ci < cpb; ++ci) {
        const int cc0 = (blockIdx.x * cpb + ci) * 128;
        __syncthreads();                             // prev phase2 done with gT

        // phase 0: g[:, cc0+c_loc] column into gT (transposed)
        {
            f32x4 acc[7] = {};
            const bf16* Wr = GW + (size_t)(cc0 + c_loc) * CDIM;
            for (int kt = 0; kt < CDIM; kt += 32) {
                const int k0 = kt + quad * 8;
                const bf16x8 bv = *(const bf16x8*)(Wr + k0);
#pragma unroll
                for (int mt = 0; mt < 7; ++mt) {
                    bf16x8 af;
                    if (ABF) {
                        af = *(const bf16x8*)((const bf16*)X + ((size_t)b * NTOK + xr[mt]) * CDIM + k0);
                    } else {
                        const float* xp = (const float*)X + ((size_t)b * NTOK + xr[mt]) * CDIM + k0;
                        const f32x4 f0 = *(const f32x4*)xp;
                        const f32x4 f1 = *(const f32x4*)(xp + 4);
#pragma unroll
                        for (int e = 0; e < 4; ++e) { af[e] = (bf16)f0[e]; af[e + 4] = (bf16)f1[e]; }
                    }
                    acc[mt] = __builtin_amdgcn_mfma_f32_16x16x32_bf16(af, bv, acc[mt], 0, 0, 0);
                }
            }
            const float gbias = GB[cc0 + c_loc];
#pragma unroll
            for (int mt = 0; mt < 7; ++mt)
#pragma unroll
                for (int r = 0; r < 4; ++r) {
                    const int m = mt * 16 + quad * 4 + r;      // 0..111
                    gT[c_loc * 136 + m] = (bf16)(acc[mt][r] + gbias);
                }
        }
        __syncthreads();

        // phase 2: y[:, chunk]
        {
            f32x4 acc[7] = {};
            for (int kt = 0; kt < RPAD; kt += 32) {
                const int k0 = kt + quad * 8;
                const bf16x8 bv = *(const bf16x8*)(gT + c_loc * 136 + k0);
#pragma unroll
                for (int mt = 0; mt < 7; ++mt) {
                    const int n = mt * 16 + lrow;
                    const bf16x8 af = *(const bf16x8*)(Rs + n * 128 + (k0 ^ ((n & 7) * 8)));
                    acc[mt] = __builtin_amdgcn_mfma_f32_16x16x32_bf16(af, bv, acc[mt], 0, 0, 0);
                }
            }
#pragma unroll
            for (int mt = 0; mt < 7; ++mt)
#pragma unroll
                for (int r = 0; r < 4; ++r) {
                    const int n = mt * 16 + quad * 4 + r;
                    if (n < NTOK)
                        Y[((size_t)b * NTOK + n) * CDIM + cc0 + c_loc] = (bf16)acc[mt][r];
                }
        }
    }
}

// ---------------------------------------------------------------------------
extern "C" void kernel_launch(void* const* d_in, const int* in_sizes, int n_in,
                              void* d_out, int out_size, void* d_ws, size_t ws_size,
                              hipStream_t stream)
{
    const float* img     = (const float*)d_in[0];
    const float* trans_w = (const float*)d_in[1];
    const float* trans_b = (const float*)d_in[2];
    const float* gw = (const float*)d_in[3],  *gb = (const float*)d_in[4];
    const float* tw = (const float*)d_in[5],  *tb = (const float*)d_in[6];
    const float* pw = (const float*)d_in[7],  *pb = (const float*)d_in[8];
    const float* ww = (const float*)d_in[9],  *wb = (const float*)d_in[10];
    const float* bng = (const float*)d_in[11], *bnb = (const float*)d_in[12];
    const float* bnm = (const float*)d_in[13], *bnv = (const float*)d_in[14];

    float* xf = (float*)d_out;   // fp32 residual master == output

    // ws layout: weights | buf1 | buf2 | [buf3] | [xb] | [imgb]
    char* ws = (char*)d_ws;
    bf16* twbf = (bf16*)ws;
    bf16* gwbf = twbf + NW_T;
    bf16* t2bf = gwbf + NW_L;
    bf16* pwbf = t2bf + NW_L;
    bf16* wwbf = pwbf + NW_L;
    bf16* buf1 = wwbf + NW_L;
    bf16* buf2 = buf1 + (size_t)MTOT * CDIM;
    bf16* buf3 = buf2 + (size_t)MTOT * CDIM;
    bf16* xb   = buf3 + (size_t)MTOT * CDIM;
    bf16* imgb = xb   + (size_t)MTOT * CDIM;

    const size_t BUF_B  = (size_t)MTOT * CDIM * 2;                  // 26,214,400
    const size_t BASE_B = (size_t)((char*)buf3 - ws);               // 67,108,864
    const size_t Y3_B   = BASE_B + BUF_B;                           // 93,323,264
    const size_t XB_B   = Y3_B + BUF_B;                             // 119,537,664
    const size_t IMG_B  = XB_B + (size_t)MTOT * 2048 * 2;           // 224,395,264

    const bool has_y3  = ws_size >= Y3_B;
    const bool has_xb  = ws_size >= XB_B;
    const bool has_img = ws_size >= IMG_B;
    const int  nsplit  = has_y3 ? 2 : 1;
    const int  cpb     = 4 / nsplit;

    const dim3 blk(256, 1, 1), blk5(512, 1, 1);
    k_cvtw<<<dim3(NW_L / 1024, 1, 5), blk, 0, stream>>>(trans_w, gw, tw, pw, ww,
                                                        twbf, gwbf, t2bf, pwbf, wwbf);
    if (has_img) {
        k_cvt<<<dim3(MTOT * 2048 / 1024), blk, 0, stream>>>(img, imgb, MTOT * 2048);
        k_enc<true><<<dim3(4, 200, 1), blk, 0, stream>>>(imgb, twbf, trans_b, xf,
                                                         has_xb ? xb : nullptr);
    } else {
        k_enc<false><<<dim3(4, 200, 1), blk, 0, stream>>>(img, twbf, trans_b, xf,
                                                          has_xb ? xb : nullptr);
    }

    for (int l = 0; l < 6; ++l) {
        const size_t wo = (size_t)l * CDIM * CDIM, bo = (size_t)l * CDIM;
        // th -> buf1, ph -> buf2
        if (has_xb)
            k_proj2<true><<<dim3(4, 200, 2), blk, 0, stream>>>(xb, t2bf + wo, tb + bo, buf1,
                                                               pwbf + wo, pb + bo, buf2);
        else
            k_proj2<false><<<dim3(4, 200, 2), blk, 0, stream>>>(xf, t2bf + wo, tb + bo, buf1,
                                                                pwbf + wo, pb + bo, buf2);
        // fused g-proj + R + y. y -> buf3 if split, else overwrites buf1 (th).
        bf16* y = has_y3 ? buf3 : buf1;
        if (has_xb)
            k_gattn<true><<<dim3(nsplit, 256, 1), blk5, 0, stream>>>(xb, gwbf + wo, gb + bo,
                                                                     buf1, buf2, y, cpb);
        else
            k_gattn<false><<<dim3(nsplit, 256, 1), blk5, 0, stream>>>(xf, gwbf + wo, gb + bo,
                                                                      buf1, buf2, y, cpb);
        bf16* xbn = (has_xb && l < 5) ? xb : nullptr;
        k_wproj<<<dim3(4, 200, 1), blk, 0, stream>>>(y, wwbf + wo, wb + bo,
                                                     bng + bo, bnb + bo,
                                                     bnm + bo, bnv + bo, xf, xbn);
    }
}